// Round 1
// baseline (665.304 us; speedup 1.0000x reference)
//
#include <hip/hip_runtime.h>
#include <cstdint>
#include <cstddef>

#define NB 512
#define N_PER 2048
#define NC 64
#define DEG 16
#define KSEL 1024
#define NTOT (NB * N_PER)        // 1048576 nodes
#define ETOT (NTOT * DEG)        // 16777216 edges
#define NOUT (NB * KSEL)         // 524288 kept nodes

// d_out layout (everything stored as float32; int values < 2^24 are exact):
//   [0)          x_out      NOUT*NC  = 33554432
//   [33554432)   new_edge   2*ETOT   = 33554432
//   [67108864)   new_batch  NOUT
//   [67633152)   perm       NOUT
//   [68157440)   score      NOUT
// total 68681728

// One block per graph: compute scores (f64 dot + tanh for ref-exact ordering),
// bitonic-sort 2048 packed keys in LDS, emit perm/score/batch + node_map.
__global__ __launch_bounds__(256) void score_sort_kernel(
    const float* __restrict__ x, const float* __restrict__ p,
    float* __restrict__ out_batch, float* __restrict__ out_perm,
    float* __restrict__ out_score, int* __restrict__ node_map,
    int* __restrict__ perm_i) {
  __shared__ double y_s[N_PER];
  __shared__ unsigned long long key_s[N_PER];
  __shared__ double p_s[NC];
  __shared__ double norm_s;

  const int tid = threadIdx.x;
  const int b = blockIdx.x;

  if (tid < NC) p_s[tid] = (double)p[tid];
  __syncthreads();
  if (tid == 0) {
    double s = 0.0;
    for (int i = 0; i < NC; ++i) s += p_s[i] * p_s[i];
    norm_s = sqrt(s);
  }
  __syncthreads();
  const double norm = norm_s;

  // 16 lanes per row, float4 per lane -> 64 channels; 16 rows per block pass.
  const int lane = tid & 15;
  const int rowg = tid >> 4;
  const double pw0 = p_s[lane * 4 + 0];
  const double pw1 = p_s[lane * 4 + 1];
  const double pw2 = p_s[lane * 4 + 2];
  const double pw3 = p_s[lane * 4 + 3];
  const float4* xrow = (const float4*)(x + (size_t)b * N_PER * NC);

  for (int r0 = 0; r0 < N_PER; r0 += 16) {
    const int row = r0 + rowg;
    float4 v = xrow[row * 16 + lane];
    double part = (double)v.x * pw0 + (double)v.y * pw1 +
                  (double)v.z * pw2 + (double)v.w * pw3;
    part += __shfl_xor(part, 8, 16);
    part += __shfl_xor(part, 4, 16);
    part += __shfl_xor(part, 2, 16);
    part += __shfl_xor(part, 1, 16);
    if (lane == 0) y_s[row] = tanh(part / norm);
  }
  __syncthreads();

  // Build 64-bit keys: ascending-sort order == descending score, tie -> lower idx.
  for (int i = tid; i < N_PER; i += 256) {
    unsigned long long u = (unsigned long long)__double_as_longlong(y_s[i]);
    unsigned long long asc =
        (u & 0x8000000000000000ULL) ? ~u : (u | 0x8000000000000000ULL);
    unsigned long long desc = ~asc;
    key_s[i] = (desc & ~2047ULL) | (unsigned long long)i;
  }
  __syncthreads();

  // Bitonic sort, ascending, 2048 elements, 1024 compare-exchanges per step.
  for (int k = 2; k <= N_PER; k <<= 1) {
    for (int j = k >> 1; j > 0; j >>= 1) {
      for (int t = tid; t < N_PER / 2; t += 256) {
        const int i = 2 * t - (t & (j - 1));
        const int partner = i + j;
        const unsigned long long a = key_s[i];
        const unsigned long long c = key_s[partner];
        const bool up = ((i & k) == 0);
        if ((a > c) == up) {
          key_s[i] = c;
          key_s[partner] = a;
        }
      }
      __syncthreads();
    }
  }

  for (int t = tid; t < N_PER; t += 256) {
    const int idx = (int)(key_s[t] & 2047ULL);
    const int g = b * N_PER + idx;
    if (t < KSEL) {
      const int nid = b * KSEL + t;
      node_map[g] = nid;
      perm_i[nid] = g;
      out_batch[nid] = (float)b;
      out_perm[nid] = (float)g;
      out_score[nid] = (float)y_s[idx];
    } else {
      node_map[g] = -1;
    }
  }
}

// x_out[r, :] = x[perm[r], :] * score[r]; 16 lanes (float4 each) per row.
__global__ __launch_bounds__(256) void gather_kernel(
    const float* __restrict__ x, const int* __restrict__ perm_i,
    const float* __restrict__ score, float* __restrict__ x_out) {
  const int t = blockIdx.x * 256 + threadIdx.x;
  const int row = t >> 4;
  const int lane = t & 15;
  const int g = perm_i[row];
  const float sc = score[row];
  float4 v = ((const float4*)x)[(size_t)g * 16 + lane];
  v.x *= sc; v.y *= sc; v.z *= sc; v.w *= sc;
  ((float4*)x_out)[(size_t)row * 16 + lane] = v;
}

// Remap edges through node_map; dropped edges -> -1 in both rows.
__global__ __launch_bounds__(256) void edge_kernel(
    const int* __restrict__ ei, const int* __restrict__ node_map,
    float* __restrict__ out_edge) {
  const int i = blockIdx.x * 256 + threadIdx.x;  // [0, ETOT/4)
  const int4 s4 = ((const int4*)ei)[i];
  const int4 d4 = ((const int4*)(ei + (size_t)ETOT))[i];
  const int ns0 = node_map[s4.x], ns1 = node_map[s4.y];
  const int ns2 = node_map[s4.z], ns3 = node_map[s4.w];
  const int nd0 = node_map[d4.x], nd1 = node_map[d4.y];
  const int nd2 = node_map[d4.z], nd3 = node_map[d4.w];
  float4 os, od;
  const bool k0 = (ns0 >= 0) && (nd0 >= 0);
  const bool k1 = (ns1 >= 0) && (nd1 >= 0);
  const bool k2 = (ns2 >= 0) && (nd2 >= 0);
  const bool k3 = (ns3 >= 0) && (nd3 >= 0);
  os.x = k0 ? (float)ns0 : -1.0f; od.x = k0 ? (float)nd0 : -1.0f;
  os.y = k1 ? (float)ns1 : -1.0f; od.y = k1 ? (float)nd1 : -1.0f;
  os.z = k2 ? (float)ns2 : -1.0f; od.z = k2 ? (float)nd2 : -1.0f;
  os.w = k3 ? (float)ns3 : -1.0f; od.w = k3 ? (float)nd3 : -1.0f;
  ((float4*)out_edge)[i] = os;
  ((float4*)(out_edge + (size_t)ETOT))[i] = od;
}

extern "C" void kernel_launch(void* const* d_in, const int* in_sizes, int n_in,
                              void* d_out, int out_size, void* d_ws,
                              size_t ws_size, hipStream_t stream) {
  const float* x = (const float*)d_in[0];
  const int* ei = (const int*)d_in[1];
  // d_in[2] = batch (implied by construction; unused)
  const float* p = (const float*)d_in[3];

  float* out = (float*)d_out;
  float* out_x = out;                       // 33554432
  float* out_edge = out + 33554432;         // 33554432
  float* out_batch = out + 67108864;        // 524288
  float* out_perm = out + 67633152;         // 524288
  float* out_score = out + 68157440;        // 524288

  int* node_map = (int*)d_ws;               // NTOT ints (4 MB)
  int* perm_i = node_map + NTOT;            // NOUT ints (2 MB)

  score_sort_kernel<<<NB, 256, 0, stream>>>(x, p, out_batch, out_perm,
                                            out_score, node_map, perm_i);
  gather_kernel<<<(NOUT * 16) / 256, 256, 0, stream>>>(x, perm_i, out_score,
                                                       out_x);
  edge_kernel<<<(ETOT / 4) / 256, 256, 0, stream>>>(ei, node_map, out_edge);
}